// Round 3
// baseline (483.594 us; speedup 1.0000x reference)
//
#include <hip/hip_runtime.h>
#include <hip/hip_bf16.h>
#include <math.h>

// Problem constants (from reference)
#define N_VARS    100000
#define D_DIM     512
#define C_CLUST   4096
#define K_VARS    32
#define E_EDGES   16384
#define S_SHARED  16
#define H_HEADS   4
#define CAP       32      // max contributions tracked per var (Poisson(2.62) -> P(>=32) ~ 1e-26)
#define NEG_SLOPE 0.2f

typedef __bf16 bf16x8_t __attribute__((ext_vector_type(8)));
typedef float  f32x4_t  __attribute__((ext_vector_type(4)));

__device__ __forceinline__ unsigned int f32_to_bf16_bits(float f) {
    unsigned int u = __builtin_bit_cast(unsigned int, f);
    unsigned int lsb = (u >> 16) & 1u;
    u += 0x7fffu + lsb;   // round-to-nearest-even
    return u >> 16;
}
__device__ __forceinline__ unsigned int pack_bf16x2(float a, float b) {
    return (f32_to_bf16_bits(b) << 16) | f32_to_bf16_bits(a);
}
__device__ __forceinline__ float bf16_lo_to_f32(unsigned int w) {
    return __builtin_bit_cast(float, w << 16);
}
__device__ __forceinline__ float bf16_hi_to_f32(unsigned int w) {
    return __builtin_bit_cast(float, w & 0xffff0000u);
}

// Robust decode of the active_heads scalar (int expected; tolerate float encoding).
__device__ __forceinline__ int decode_active_heads(const int* p) {
    int raw = p[0];
    if (raw >= 1 && raw <= H_HEADS) return raw;
    float f = __builtin_bit_cast(float, raw);
    if (f >= 1.0f && f <= (float)H_HEADS) return (int)f;
    return H_HEADS;
}

// ---------------------------------------------------------------------------
// 0a) Convert the three 512x512 f32 weight matrices to bf16 (packed u32 pairs).
__global__ void convert_w_kernel(const float* __restrict__ Wq,
                                 const float* __restrict__ Wk,
                                 const float* __restrict__ Wv,
                                 unsigned int* __restrict__ Wb) {
    const float* W = (blockIdx.y == 0) ? Wq : (blockIdx.y == 1) ? Wk : Wv;
    int i = blockIdx.x * blockDim.x + threadIdx.x;         // word index [0, 512*512/2)
    float2 w = ((const float2*)W)[i];
    Wb[(size_t)blockIdx.y * (D_DIM * D_DIM / 2) + i] = pack_bf16x2(w.x, w.y);
}

// 0b) Transposed bf16 copies of Wq, Wk (for M = Wq^T @ Wk via MFMA, which
//     needs k contiguous in both operands). 32x32 LDS tiles, grid (16,16,2).
__global__ void transpose_w_kernel(const float* __restrict__ Wq,
                                   const float* __restrict__ Wk,
                                   unsigned short* __restrict__ WqT,
                                   unsigned short* __restrict__ WkT) {
    __shared__ float tile[32][33];
    const float* W = blockIdx.z ? Wk : Wq;
    unsigned short* O = blockIdx.z ? WkT : WqT;
    int r0 = blockIdx.y * 32, c0 = blockIdx.x * 32;
    int tx = threadIdx.x & 31, ty = threadIdx.x >> 5;   // block 256 = 32x8
#pragma unroll
    for (int i = 0; i < 32; i += 8)
        tile[ty + i][tx] = W[(size_t)(r0 + ty + i) * D_DIM + c0 + tx];
    __syncthreads();
#pragma unroll
    for (int i = 0; i < 32; i += 8)
        O[(size_t)(c0 + ty + i) * D_DIM + r0 + tx] =
            (unsigned short)f32_to_bf16_bits(tile[tx][ty + i]);
}

// ---------------------------------------------------------------------------
// 1) Per-cluster mean pool. 2 clusters per 256-block; 128 threads/cluster.
//    Also zeroes counts[] (grid covers N_VARS), replacing the memset dispatch.
__global__ void pool_kernel(const float* __restrict__ x,
                            const int* __restrict__ cvid,
                            uint2* __restrict__ cfb /* packed bf16, 4/entry */,
                            int* __restrict__ counts) {
    int gtid = blockIdx.x * blockDim.x + threadIdx.x;
    if (gtid < N_VARS) counts[gtid] = 0;

    int c = blockIdx.x * 2 + (threadIdx.x >> 7);
    c = __builtin_amdgcn_readfirstlane(c);   // wave-uniform -> scalar id loads
    int t = threadIdx.x & 127;  // float4 index within row
    const int* cv = cvid + c * K_VARS;
    float4 acc = {0.f, 0.f, 0.f, 0.f};
#pragma unroll 8
    for (int k = 0; k < K_VARS; ++k) {
        int v = cv[k];                       // s_load (scalar addr)
        float4 w = ((const float4*)(x + (size_t)v * D_DIM))[t];
        acc.x += w.x; acc.y += w.y; acc.z += w.z; acc.w += w.w;
    }
    const float inv = 1.0f / (float)K_VARS;
    uint2 o;
    o.x = pack_bf16x2(acc.x * inv, acc.y * inv);
    o.y = pack_bf16x2(acc.z * inv, acc.w * inv);
    cfb[(size_t)c * (D_DIM / 4) + t] = o;
}

// ---------------------------------------------------------------------------
// Shared MFMA tile body: O[m,n] = sum_k A[m,k] * B[n,k], 64x64 block tile,
// 4 waves, K=512, bf16 output. (16x16x32 bf16 MFMA, layout m89-verified.)
__device__ __forceinline__ void gemm_tile_bf16out(
        const unsigned short* __restrict__ A,
        const unsigned short* __restrict__ B,
        unsigned short* __restrict__ O,
        int m0_block, int n0) {
    int wave = threadIdx.x >> 6;
    int lane = threadIdx.x & 63;
    int m0 = m0_block + wave * 16;
    int mr = m0 + (lane & 15);
    int kb = (lane >> 4) * 8;

    f32x4_t acc0 = {0.f,0.f,0.f,0.f}, acc1 = {0.f,0.f,0.f,0.f};
    f32x4_t acc2 = {0.f,0.f,0.f,0.f}, acc3 = {0.f,0.f,0.f,0.f};
    const unsigned short* arow = A + (size_t)mr * D_DIM + kb;
    const unsigned short* b0r  = B + (size_t)(n0 +  0 + (lane & 15)) * D_DIM + kb;
    const unsigned short* b1r  = B + (size_t)(n0 + 16 + (lane & 15)) * D_DIM + kb;
    const unsigned short* b2r  = B + (size_t)(n0 + 32 + (lane & 15)) * D_DIM + kb;
    const unsigned short* b3r  = B + (size_t)(n0 + 48 + (lane & 15)) * D_DIM + kb;
#pragma unroll 4
    for (int k0 = 0; k0 < D_DIM; k0 += 32) {
        bf16x8_t a  = *(const bf16x8_t*)(arow + k0);
        bf16x8_t b0 = *(const bf16x8_t*)(b0r + k0);
        bf16x8_t b1 = *(const bf16x8_t*)(b1r + k0);
        bf16x8_t b2 = *(const bf16x8_t*)(b2r + k0);
        bf16x8_t b3 = *(const bf16x8_t*)(b3r + k0);
        acc0 = __builtin_amdgcn_mfma_f32_16x16x32_bf16(a, b0, acc0, 0, 0, 0);
        acc1 = __builtin_amdgcn_mfma_f32_16x16x32_bf16(a, b1, acc1, 0, 0, 0);
        acc2 = __builtin_amdgcn_mfma_f32_16x16x32_bf16(a, b2, acc2, 0, 0, 0);
        acc3 = __builtin_amdgcn_mfma_f32_16x16x32_bf16(a, b3, acc3, 0, 0, 0);
    }
    // C/D layout: col = lane&15 (n), row = (lane>>4)*4 + reg (m)
    int rb = m0 + (lane >> 4) * 4;
    int cl = lane & 15;
#pragma unroll
    for (int r = 0; r < 4; ++r) {
        unsigned short* orow = O + (size_t)(rb + r) * D_DIM + n0 + cl;
        orow[ 0] = (unsigned short)f32_to_bf16_bits(acc0[r]);
        orow[16] = (unsigned short)f32_to_bf16_bits(acc1[r]);
        orow[32] = (unsigned short)f32_to_bf16_bits(acc2[r]);
        orow[48] = (unsigned short)f32_to_bf16_bits(acc3[r]);
    }
}

// 2a) M = Wq^T @ Wk  (512x512, bf16 out). M[m,n] = sum_k WqT[m,k]*WkT[n,k].
__global__ __launch_bounds__(256) void gemm_m_kernel(
        const unsigned short* __restrict__ WqT,
        const unsigned short* __restrict__ WkT,
        unsigned short* __restrict__ Mb) {
    gemm_tile_bf16out(WqT, WkT, Mb, blockIdx.x * 64, blockIdx.y * 64);
}

// 2b) T = cf @ M^T (z=0) and V = cf @ Wv^T (z=1), both bf16 out.
//     score_e = dot(cf[c1], T[c2]) == dot(Q[c1], K[c2])  (M-trick).
__global__ __launch_bounds__(256) void gemm_tv_kernel(
        const unsigned short* __restrict__ cfb,
        const unsigned short* __restrict__ Mb,
        const unsigned short* __restrict__ Wvb,
        unsigned short* __restrict__ Tb,
        unsigned short* __restrict__ Vb) {
    const unsigned short* B = (blockIdx.z == 0) ? Mb : Wvb;
    unsigned short* O = (blockIdx.z == 0) ? Tb : Vb;
    gemm_tile_bf16out(cfb, B, O, blockIdx.x * 64, blockIdx.y * 64);
}

// ---------------------------------------------------------------------------
// 3) Fused edge attention + scatter-fill. One wave per edge.
//    score = dot(cf[c1], T[c2]) over bf16 rows (1 KB each, L2-resident).
//    Lanes 0..15 push packed (attn_bf16 << 16 | c2) into shared vars' buckets.
__global__ __launch_bounds__(256) void score_fill_kernel(
        const unsigned short* __restrict__ cfb,
        const unsigned short* __restrict__ Tb,
        const int* __restrict__ cei,
        const float* __restrict__ hw,
        const int* __restrict__ active_heads,
        const int* __restrict__ shared_vars,
        int* __restrict__ counts,
        unsigned int* __restrict__ bucket) {
    int e = __builtin_amdgcn_readfirstlane(blockIdx.x * 4 + (threadIdx.x >> 6));
    int lane = threadIdx.x & 63;
    int c1 = cei[e];
    int c2 = cei[E_EDGES + e];
    // one uint4 (8 bf16) per lane covers the 512-dim row
    uint4 qa = ((const uint4*)(cfb + (size_t)c1 * D_DIM))[lane];
    uint4 ta = ((const uint4*)(Tb  + (size_t)c2 * D_DIM))[lane];
    float s = bf16_lo_to_f32(qa.x) * bf16_lo_to_f32(ta.x)
            + bf16_hi_to_f32(qa.x) * bf16_hi_to_f32(ta.x)
            + bf16_lo_to_f32(qa.y) * bf16_lo_to_f32(ta.y)
            + bf16_hi_to_f32(qa.y) * bf16_hi_to_f32(ta.y)
            + bf16_lo_to_f32(qa.z) * bf16_lo_to_f32(ta.z)
            + bf16_hi_to_f32(qa.z) * bf16_hi_to_f32(ta.z)
            + bf16_lo_to_f32(qa.w) * bf16_lo_to_f32(ta.w)
            + bf16_hi_to_f32(qa.w) * bf16_hi_to_f32(ta.w);
#pragma unroll
    for (int off = 32; off > 0; off >>= 1)
        s += __shfl_xor(s, off);
    // all lanes now hold the full dot product
    int ah = decode_active_heads(active_heads);
    float m = 0.f;
    for (int h = 0; h < ah; ++h) m += hw[h];
    m /= (float)ah;
    float sc = s * (1.0f / sqrtf((float)D_DIM));
    sc = sc >= 0.f ? sc : NEG_SLOPE * sc;
    float attn = m / (1.f + __expf(-sc));
    unsigned int packed = (f32_to_bf16_bits(attn) << 16) | (unsigned int)c2;
    if (lane < S_SHARED) {
        int v = shared_vars[e * S_SHARED + lane];
        int pos = atomicAdd(&counts[v], 1);
        if (pos < CAP) bucket[(size_t)v * CAP + pos] = packed;
    }
}

// ---------------------------------------------------------------------------
// 4) Gather: 1 var per wave (4 vars / 256-block). Lane owns dims
//    [8*lane, 8*lane+8): two consecutive float4 of x (non-temporal: x is dead
//    after this kernel; keeps V/bucket L2-resident), ONE dwordx4 of bf16 V per
//    contribution. Chain depth 2 (bucket -> V); next quad prefetched.
__global__ __launch_bounds__(256) void gather_kernel(
        const float* __restrict__ x,
        const unsigned short* __restrict__ V,
        const int* __restrict__ counts,
        const unsigned int* __restrict__ bucket,
        float* __restrict__ out) {
    int v = __builtin_amdgcn_readfirstlane(blockIdx.x * 4 + (threadIdx.x >> 6));
    int lane = threadIdx.x & 63;
    const f32x4_t* xr = (const f32x4_t*)(x + (size_t)v * D_DIM);
    f32x4_t a0 = __builtin_nontemporal_load(xr + 2 * lane);      // dims 8l..8l+3
    f32x4_t a1 = __builtin_nontemporal_load(xr + 2 * lane + 1);  // dims 8l+4..8l+7
    int cnt = counts[v];
    if (cnt > CAP) cnt = CAP;
    const unsigned int* bk = bucket + (size_t)v * CAP;
    uint4 pw = *(const uint4*)bk;       // unconditional: issued alongside counts/x

    int k = 0;
    while (k < cnt) {
        int m = cnt - k;                // wave-uniform
        // Issue all V-row loads of this group before any accumulation (MLP).
        uint4 w0, w1, w2, w3;
        w0 = ((const uint4*)(V + (size_t)(pw.x & 0xFFFu) * D_DIM))[lane];
        if (m > 1) w1 = ((const uint4*)(V + (size_t)(pw.y & 0xFFFu) * D_DIM))[lane];
        if (m > 2) w2 = ((const uint4*)(V + (size_t)(pw.z & 0xFFFu) * D_DIM))[lane];
        if (m > 3) w3 = ((const uint4*)(V + (size_t)(pw.w & 0xFFFu) * D_DIM))[lane];
        // Prefetch next bucket quad (scalar) before the VALU tail.
        uint4 pwn;
        int kn = k + 4;
        if (kn < cnt) pwn = *(const uint4*)(bk + kn);

        {
            float at = __builtin_bit_cast(float, pw.x & 0xffff0000u);
            a0[0] += at * bf16_lo_to_f32(w0.x); a0[1] += at * bf16_hi_to_f32(w0.x);
            a0[2] += at * bf16_lo_to_f32(w0.y); a0[3] += at * bf16_hi_to_f32(w0.y);
            a1[0] += at * bf16_lo_to_f32(w0.z); a1[1] += at * bf16_hi_to_f32(w0.z);
            a1[2] += at * bf16_lo_to_f32(w0.w); a1[3] += at * bf16_hi_to_f32(w0.w);
        }
        if (m > 1) {
            float at = __builtin_bit_cast(float, pw.y & 0xffff0000u);
            a0[0] += at * bf16_lo_to_f32(w1.x); a0[1] += at * bf16_hi_to_f32(w1.x);
            a0[2] += at * bf16_lo_to_f32(w1.y); a0[3] += at * bf16_hi_to_f32(w1.y);
            a1[0] += at * bf16_lo_to_f32(w1.z); a1[1] += at * bf16_hi_to_f32(w1.z);
            a1[2] += at * bf16_lo_to_f32(w1.w); a1[3] += at * bf16_hi_to_f32(w1.w);
        }
        if (m > 2) {
            float at = __builtin_bit_cast(float, pw.z & 0xffff0000u);
            a0[0] += at * bf16_lo_to_f32(w2.x); a0[1] += at * bf16_hi_to_f32(w2.x);
            a0[2] += at * bf16_lo_to_f32(w2.y); a0[3] += at * bf16_hi_to_f32(w2.y);
            a1[0] += at * bf16_lo_to_f32(w2.z); a1[1] += at * bf16_hi_to_f32(w2.z);
            a1[2] += at * bf16_lo_to_f32(w2.w); a1[3] += at * bf16_hi_to_f32(w2.w);
        }
        if (m > 3) {
            float at = __builtin_bit_cast(float, pw.w & 0xffff0000u);
            a0[0] += at * bf16_lo_to_f32(w3.x); a0[1] += at * bf16_hi_to_f32(w3.x);
            a0[2] += at * bf16_lo_to_f32(w3.y); a0[3] += at * bf16_hi_to_f32(w3.y);
            a1[0] += at * bf16_lo_to_f32(w3.z); a1[1] += at * bf16_hi_to_f32(w3.z);
            a1[2] += at * bf16_lo_to_f32(w3.w); a1[3] += at * bf16_hi_to_f32(w3.w);
        }
        pw = pwn;
        k = kn;
    }
    // out is written once and never re-read: non-temporal keeps caches for x/V.
    f32x4_t* orow = (f32x4_t*)(out + (size_t)v * D_DIM);
    __builtin_nontemporal_store(a0, orow + 2 * lane);
    __builtin_nontemporal_store(a1, orow + 2 * lane + 1);
}

// ---------------------------------------------------------------------------
extern "C" void kernel_launch(void* const* d_in, const int* in_sizes, int n_in,
                              void* d_out, int out_size, void* d_ws, size_t ws_size,
                              hipStream_t stream) {
    const float* x_var = (const float*)d_in[0];
    const float* W_Q   = (const float*)d_in[1];
    const float* W_K   = (const float*)d_in[2];
    const float* W_V   = (const float*)d_in[3];
    const float* hw    = (const float*)d_in[4];
    const int* cvid  = (const int*)d_in[5];
    const int* cei   = (const int*)d_in[6];
    const int* shv   = (const int*)d_in[7];
    const int* ahp   = (const int*)d_in[8];

    char* ws = (char*)d_ws;
    const size_t MiB = 1024 * 1024;
    const size_t KiB = 1024;
    // workspace layout (~30 MiB total)
    unsigned int*   cfb  = (unsigned int*)(ws + 0);                 // bf16 [C,D]: 4 MiB
    unsigned int*   Wb   = (unsigned int*)(ws + 4 * MiB);           // bf16 3x[D,D]: 1.5 MiB
    unsigned short* WqT  = (unsigned short*)(ws + 5 * MiB + 512*KiB); // 512 KiB
    unsigned short* WkT  = (unsigned short*)(ws + 6 * MiB);         // 512 KiB
    unsigned short* Mb   = (unsigned short*)(ws + 7 * MiB);         // bf16 [D,D]: 512 KiB
    unsigned short* Tb   = (unsigned short*)(ws + 8 * MiB);         // bf16 [C,D]: 4 MiB
    unsigned short* Vb   = (unsigned short*)(ws + 12 * MiB);        // bf16 [C,D]: 4 MiB
    int* counts          = (int*)(ws + 16 * MiB);                   // 400 KB
    unsigned int* bucket = (unsigned int*)(ws + 17 * MiB);          // 12.8 MB

    convert_w_kernel<<<dim3(D_DIM * D_DIM / 2 / 256, 3), 256, 0, stream>>>(
        W_Q, W_K, W_V, Wb);

    transpose_w_kernel<<<dim3(16, 16, 2), 256, 0, stream>>>(W_Q, W_K, WqT, WkT);

    pool_kernel<<<C_CLUST / 2, 256, 0, stream>>>(x_var, cvid, (uint2*)cfb, counts);

    gemm_m_kernel<<<dim3(D_DIM / 64, D_DIM / 64), 256, 0, stream>>>(WqT, WkT, Mb);

    gemm_tv_kernel<<<dim3(C_CLUST / 64, D_DIM / 64, 2), 256, 0, stream>>>(
        (const unsigned short*)cfb, Mb,
        (const unsigned short*)Wb + 2 * (size_t)D_DIM * D_DIM, Tb, Vb);

    score_fill_kernel<<<E_EDGES / 4, 256, 0, stream>>>(
        (const unsigned short*)cfb, Tb, cei, hw, ahp, shv, counts, bucket);

    gather_kernel<<<N_VARS / 4, 256, 0, stream>>>(x_var, Vb, counts, bucket,
                                                  (float*)d_out);
}

// Round 4
// 471.143 us; speedup vs baseline: 1.0264x; 1.0264x over previous
//
#include <hip/hip_runtime.h>
#include <hip/hip_bf16.h>
#include <math.h>

// Problem constants (from reference)
#define N_VARS    100000
#define D_DIM     512
#define C_CLUST   4096
#define K_VARS    32
#define E_EDGES   16384
#define S_SHARED  16
#define H_HEADS   4
#define CAP       32      // max contributions tracked per var (Poisson(2.62) -> P(>=32) ~ 1e-26)
#define NEG_SLOPE 0.2f

typedef __bf16 bf16x8_t __attribute__((ext_vector_type(8)));
typedef float  f32x4_t  __attribute__((ext_vector_type(4)));

__device__ __forceinline__ unsigned int f32_to_bf16_bits(float f) {
    unsigned int u = __builtin_bit_cast(unsigned int, f);
    unsigned int lsb = (u >> 16) & 1u;
    u += 0x7fffu + lsb;   // round-to-nearest-even
    return u >> 16;
}
__device__ __forceinline__ unsigned int pack_bf16x2(float a, float b) {
    return (f32_to_bf16_bits(b) << 16) | f32_to_bf16_bits(a);
}
__device__ __forceinline__ float bf16_lo_to_f32(unsigned int w) {
    return __builtin_bit_cast(float, w << 16);
}
__device__ __forceinline__ float bf16_hi_to_f32(unsigned int w) {
    return __builtin_bit_cast(float, w & 0xffff0000u);
}

// Robust decode of the active_heads scalar (int expected; tolerate float encoding).
__device__ __forceinline__ int decode_active_heads(const int* p) {
    int raw = p[0];
    if (raw >= 1 && raw <= H_HEADS) return raw;
    float f = __builtin_bit_cast(float, raw);
    if (f >= 1.0f && f <= (float)H_HEADS) return (int)f;
    return H_HEADS;
}

// ---------------------------------------------------------------------------
// 0) prep: one dispatch, block-range partitioned.
//    blocks [0,512):    transpose Wq,Wk -> bf16 WqT,WkT (32x32 LDS tiles;
//                       256 tiles per matrix, matrix = bid>>8)
//    blocks [512,2048): convert Wq,Wk,Wv -> packed bf16 Wb (256 words/block;
//                       1536*256 == 3*512*512/2 exactly); these threads also
//                       zero counts[] (393216 threads >= N_VARS).
__global__ __launch_bounds__(256) void prep_kernel(
        const float* __restrict__ Wq,
        const float* __restrict__ Wk,
        const float* __restrict__ Wv,
        unsigned int* __restrict__ Wb,
        unsigned short* __restrict__ WqT,
        unsigned short* __restrict__ WkT,
        int* __restrict__ counts) {
    __shared__ float tile[32][33];
    int bid = blockIdx.x;
    if (bid < 512) {
        int mtx = bid >> 8;              // 0 = Wq, 1 = Wk
        int t = bid & 255;
        int r0 = (t >> 4) * 32, c0 = (t & 15) * 32;
        const float* W = mtx ? Wk : Wq;
        unsigned short* O = mtx ? WkT : WqT;
        int tx = threadIdx.x & 31, ty = threadIdx.x >> 5;   // 32x8
#pragma unroll
        for (int i = 0; i < 32; i += 8)
            tile[ty + i][tx] = W[(size_t)(r0 + ty + i) * D_DIM + c0 + tx];
        __syncthreads();
#pragma unroll
        for (int i = 0; i < 32; i += 8)
            O[(size_t)(c0 + ty + i) * D_DIM + r0 + tx] =
                (unsigned short)f32_to_bf16_bits(tile[tx][ty + i]);
    } else {
        int j = (bid - 512) * 256 + threadIdx.x;   // [0, 393216)
        if (j < N_VARS) counts[j] = 0;
        int mtx = j / (D_DIM * D_DIM / 2);         // 0,1,2
        int i = j - mtx * (D_DIM * D_DIM / 2);
        const float* W = (mtx == 0) ? Wq : (mtx == 1) ? Wk : Wv;
        float2 w = ((const float2*)W)[i];
        Wb[(size_t)j] = pack_bf16x2(w.x, w.y);
    }
}

// ---------------------------------------------------------------------------
// Shared MFMA tile body: O[m,n] = sum_k A[m,k] * B[n,k], 64x64 block tile,
// 4 waves, K=512, bf16 output. (16x16x32 bf16 MFMA, layout m89-verified.)
__device__ __forceinline__ void gemm_tile_bf16out(
        const unsigned short* __restrict__ A,
        const unsigned short* __restrict__ B,
        unsigned short* __restrict__ O,
        int m0_block, int n0) {
    int wave = threadIdx.x >> 6;
    int lane = threadIdx.x & 63;
    int m0 = m0_block + wave * 16;
    int mr = m0 + (lane & 15);
    int kb = (lane >> 4) * 8;

    f32x4_t acc0 = {0.f,0.f,0.f,0.f}, acc1 = {0.f,0.f,0.f,0.f};
    f32x4_t acc2 = {0.f,0.f,0.f,0.f}, acc3 = {0.f,0.f,0.f,0.f};
    const unsigned short* arow = A + (size_t)mr * D_DIM + kb;
    const unsigned short* b0r  = B + (size_t)(n0 +  0 + (lane & 15)) * D_DIM + kb;
    const unsigned short* b1r  = B + (size_t)(n0 + 16 + (lane & 15)) * D_DIM + kb;
    const unsigned short* b2r  = B + (size_t)(n0 + 32 + (lane & 15)) * D_DIM + kb;
    const unsigned short* b3r  = B + (size_t)(n0 + 48 + (lane & 15)) * D_DIM + kb;
#pragma unroll 4
    for (int k0 = 0; k0 < D_DIM; k0 += 32) {
        bf16x8_t a  = *(const bf16x8_t*)(arow + k0);
        bf16x8_t b0 = *(const bf16x8_t*)(b0r + k0);
        bf16x8_t b1 = *(const bf16x8_t*)(b1r + k0);
        bf16x8_t b2 = *(const bf16x8_t*)(b2r + k0);
        bf16x8_t b3 = *(const bf16x8_t*)(b3r + k0);
        acc0 = __builtin_amdgcn_mfma_f32_16x16x32_bf16(a, b0, acc0, 0, 0, 0);
        acc1 = __builtin_amdgcn_mfma_f32_16x16x32_bf16(a, b1, acc1, 0, 0, 0);
        acc2 = __builtin_amdgcn_mfma_f32_16x16x32_bf16(a, b2, acc2, 0, 0, 0);
        acc3 = __builtin_amdgcn_mfma_f32_16x16x32_bf16(a, b3, acc3, 0, 0, 0);
    }
    // C/D layout: col = lane&15 (n), row = (lane>>4)*4 + reg (m)
    int rb = m0 + (lane >> 4) * 4;
    int cl = lane & 15;
#pragma unroll
    for (int r = 0; r < 4; ++r) {
        unsigned short* orow = O + (size_t)(rb + r) * D_DIM + n0 + cl;
        orow[ 0] = (unsigned short)f32_to_bf16_bits(acc0[r]);
        orow[16] = (unsigned short)f32_to_bf16_bits(acc1[r]);
        orow[32] = (unsigned short)f32_to_bf16_bits(acc2[r]);
        orow[48] = (unsigned short)f32_to_bf16_bits(acc3[r]);
    }
}

// ---------------------------------------------------------------------------
// 1) pool + gemm_m in one dispatch (independent: gemm_m needs WqT/WkT from
//    prep; pool needs x/cvid). blocks [0,64): M = Wq^T @ Wk (8x8 64-tiles).
//    blocks [64, 2112): mean-pool, 2 clusters per block.
__global__ __launch_bounds__(256) void pool_m_kernel(
        const float* __restrict__ x,
        const int* __restrict__ cvid,
        uint2* __restrict__ cfb /* packed bf16, 4/entry */,
        const unsigned short* __restrict__ WqT,
        const unsigned short* __restrict__ WkT,
        unsigned short* __restrict__ Mb) {
    int bid = blockIdx.x;
    if (bid < 64) {
        gemm_tile_bf16out(WqT, WkT, Mb, (bid >> 3) * 64, (bid & 7) * 64);
        return;
    }
    int c = (bid - 64) * 2 + (threadIdx.x >> 7);
    c = __builtin_amdgcn_readfirstlane(c);   // wave-uniform -> scalar id loads
    int t = threadIdx.x & 127;  // float4 index within row
    const int* cv = cvid + c * K_VARS;
    float4 acc = {0.f, 0.f, 0.f, 0.f};
#pragma unroll 8
    for (int k = 0; k < K_VARS; ++k) {
        int v = cv[k];                       // s_load (scalar addr)
        float4 w = ((const float4*)(x + (size_t)v * D_DIM))[t];
        acc.x += w.x; acc.y += w.y; acc.z += w.z; acc.w += w.w;
    }
    const float inv = 1.0f / (float)K_VARS;
    uint2 o;
    o.x = pack_bf16x2(acc.x * inv, acc.y * inv);
    o.y = pack_bf16x2(acc.z * inv, acc.w * inv);
    cfb[(size_t)c * (D_DIM / 4) + t] = o;
}

// ---------------------------------------------------------------------------
// 2) T = cf @ M^T (z=0) and V = cf @ Wv^T (z=1), both bf16 out.
//    score_e = dot(cf[c1], T[c2]) == dot(Q[c1], K[c2])  (M-trick).
__global__ __launch_bounds__(256) void gemm_tv_kernel(
        const unsigned short* __restrict__ cfb,
        const unsigned short* __restrict__ Mb,
        const unsigned short* __restrict__ Wvb,
        unsigned short* __restrict__ Tb,
        unsigned short* __restrict__ Vb) {
    const unsigned short* B = (blockIdx.z == 0) ? Mb : Wvb;
    unsigned short* O = (blockIdx.z == 0) ? Tb : Vb;
    gemm_tile_bf16out(cfb, B, O, blockIdx.x * 64, blockIdx.y * 64);
}

// ---------------------------------------------------------------------------
// 3) Fused edge attention + scatter-fill. One wave per edge.
//    score = dot(cf[c1], T[c2]) over bf16 rows (1 KB each, L2-resident).
//    Lanes 0..15 push packed (attn_bf16 << 16 | c2) into shared vars' buckets.
__global__ __launch_bounds__(256) void score_fill_kernel(
        const unsigned short* __restrict__ cfb,
        const unsigned short* __restrict__ Tb,
        const int* __restrict__ cei,
        const float* __restrict__ hw,
        const int* __restrict__ active_heads,
        const int* __restrict__ shared_vars,
        int* __restrict__ counts,
        unsigned int* __restrict__ bucket) {
    int e = __builtin_amdgcn_readfirstlane(blockIdx.x * 4 + (threadIdx.x >> 6));
    int lane = threadIdx.x & 63;
    int c1 = cei[e];
    int c2 = cei[E_EDGES + e];
    // one uint4 (8 bf16) per lane covers the 512-dim row
    uint4 qa = ((const uint4*)(cfb + (size_t)c1 * D_DIM))[lane];
    uint4 ta = ((const uint4*)(Tb  + (size_t)c2 * D_DIM))[lane];
    float s = bf16_lo_to_f32(qa.x) * bf16_lo_to_f32(ta.x)
            + bf16_hi_to_f32(qa.x) * bf16_hi_to_f32(ta.x)
            + bf16_lo_to_f32(qa.y) * bf16_lo_to_f32(ta.y)
            + bf16_hi_to_f32(qa.y) * bf16_hi_to_f32(ta.y)
            + bf16_lo_to_f32(qa.z) * bf16_lo_to_f32(ta.z)
            + bf16_hi_to_f32(qa.z) * bf16_hi_to_f32(ta.z)
            + bf16_lo_to_f32(qa.w) * bf16_lo_to_f32(ta.w)
            + bf16_hi_to_f32(qa.w) * bf16_hi_to_f32(ta.w);
#pragma unroll
    for (int off = 32; off > 0; off >>= 1)
        s += __shfl_xor(s, off);
    // all lanes now hold the full dot product
    int ah = decode_active_heads(active_heads);
    float m = 0.f;
    for (int h = 0; h < ah; ++h) m += hw[h];
    m /= (float)ah;
    float sc = s * (1.0f / sqrtf((float)D_DIM));
    sc = sc >= 0.f ? sc : NEG_SLOPE * sc;
    float attn = m / (1.f + __expf(-sc));
    unsigned int packed = (f32_to_bf16_bits(attn) << 16) | (unsigned int)c2;
    if (lane < S_SHARED) {
        int v = shared_vars[e * S_SHARED + lane];
        int pos = atomicAdd(&counts[v], 1);
        if (pos < CAP) bucket[(size_t)v * CAP + pos] = packed;
    }
}

// ---------------------------------------------------------------------------
// 4) Gather: 1 var per wave (4 vars / 256-block). Lane owns dims
//    [8*lane, 8*lane+8): two consecutive float4 of x (non-temporal: x is dead
//    after this kernel; NT still hits L3 if pool left the row resident), ONE
//    dwordx4 of bf16 V per contribution. Chain depth 2 (bucket -> V).
__global__ __launch_bounds__(256) void gather_kernel(
        const float* __restrict__ x,
        const unsigned short* __restrict__ V,
        const int* __restrict__ counts,
        const unsigned int* __restrict__ bucket,
        float* __restrict__ out) {
    int v = __builtin_amdgcn_readfirstlane(blockIdx.x * 4 + (threadIdx.x >> 6));
    int lane = threadIdx.x & 63;
    const f32x4_t* xr = (const f32x4_t*)(x + (size_t)v * D_DIM);
    f32x4_t a0 = __builtin_nontemporal_load(xr + 2 * lane);      // dims 8l..8l+3
    f32x4_t a1 = __builtin_nontemporal_load(xr + 2 * lane + 1);  // dims 8l+4..8l+7
    int cnt = counts[v];
    if (cnt > CAP) cnt = CAP;
    const unsigned int* bk = bucket + (size_t)v * CAP;
    uint4 pw = *(const uint4*)bk;       // unconditional: issued alongside counts/x

    int k = 0;
    while (k < cnt) {
        int m = cnt - k;                // wave-uniform
        // Issue all V-row loads of this group before any accumulation (MLP).
        uint4 w0, w1, w2, w3;
        w0 = ((const uint4*)(V + (size_t)(pw.x & 0xFFFu) * D_DIM))[lane];
        if (m > 1) w1 = ((const uint4*)(V + (size_t)(pw.y & 0xFFFu) * D_DIM))[lane];
        if (m > 2) w2 = ((const uint4*)(V + (size_t)(pw.z & 0xFFFu) * D_DIM))[lane];
        if (m > 3) w3 = ((const uint4*)(V + (size_t)(pw.w & 0xFFFu) * D_DIM))[lane];
        // Prefetch next bucket quad (scalar) before the VALU tail.
        uint4 pwn;
        int kn = k + 4;
        if (kn < cnt) pwn = *(const uint4*)(bk + kn);

        {
            float at = __builtin_bit_cast(float, pw.x & 0xffff0000u);
            a0[0] += at * bf16_lo_to_f32(w0.x); a0[1] += at * bf16_hi_to_f32(w0.x);
            a0[2] += at * bf16_lo_to_f32(w0.y); a0[3] += at * bf16_hi_to_f32(w0.y);
            a1[0] += at * bf16_lo_to_f32(w0.z); a1[1] += at * bf16_hi_to_f32(w0.z);
            a1[2] += at * bf16_lo_to_f32(w0.w); a1[3] += at * bf16_hi_to_f32(w0.w);
        }
        if (m > 1) {
            float at = __builtin_bit_cast(float, pw.y & 0xffff0000u);
            a0[0] += at * bf16_lo_to_f32(w1.x); a0[1] += at * bf16_hi_to_f32(w1.x);
            a0[2] += at * bf16_lo_to_f32(w1.y); a0[3] += at * bf16_hi_to_f32(w1.y);
            a1[0] += at * bf16_lo_to_f32(w1.z); a1[1] += at * bf16_hi_to_f32(w1.z);
            a1[2] += at * bf16_lo_to_f32(w1.w); a1[3] += at * bf16_hi_to_f32(w1.w);
        }
        if (m > 2) {
            float at = __builtin_bit_cast(float, pw.z & 0xffff0000u);
            a0[0] += at * bf16_lo_to_f32(w2.x); a0[1] += at * bf16_hi_to_f32(w2.x);
            a0[2] += at * bf16_lo_to_f32(w2.y); a0[3] += at * bf16_hi_to_f32(w2.y);
            a1[0] += at * bf16_lo_to_f32(w2.z); a1[1] += at * bf16_hi_to_f32(w2.z);
            a1[2] += at * bf16_lo_to_f32(w2.w); a1[3] += at * bf16_hi_to_f32(w2.w);
        }
        if (m > 3) {
            float at = __builtin_bit_cast(float, pw.w & 0xffff0000u);
            a0[0] += at * bf16_lo_to_f32(w3.x); a0[1] += at * bf16_hi_to_f32(w3.x);
            a0[2] += at * bf16_lo_to_f32(w3.y); a0[3] += at * bf16_hi_to_f32(w3.y);
            a1[0] += at * bf16_lo_to_f32(w3.z); a1[1] += at * bf16_hi_to_f32(w3.z);
            a1[2] += at * bf16_lo_to_f32(w3.w); a1[3] += at * bf16_hi_to_f32(w3.w);
        }
        pw = pwn;
        k = kn;
    }
    // out is written once and never re-read: non-temporal keeps caches for x/V.
    f32x4_t* orow = (f32x4_t*)(out + (size_t)v * D_DIM);
    __builtin_nontemporal_store(a0, orow + 2 * lane);
    __builtin_nontemporal_store(a1, orow + 2 * lane + 1);
}

// ---------------------------------------------------------------------------
extern "C" void kernel_launch(void* const* d_in, const int* in_sizes, int n_in,
                              void* d_out, int out_size, void* d_ws, size_t ws_size,
                              hipStream_t stream) {
    const float* x_var = (const float*)d_in[0];
    const float* W_Q   = (const float*)d_in[1];
    const float* W_K   = (const float*)d_in[2];
    const float* W_V   = (const float*)d_in[3];
    const float* hw    = (const float*)d_in[4];
    const int* cvid  = (const int*)d_in[5];
    const int* cei   = (const int*)d_in[6];
    const int* shv   = (const int*)d_in[7];
    const int* ahp   = (const int*)d_in[8];

    char* ws = (char*)d_ws;
    const size_t MiB = 1024 * 1024;
    const size_t KiB = 1024;
    // workspace layout (~30 MiB total)
    unsigned int*   cfb  = (unsigned int*)(ws + 0);                 // bf16 [C,D]: 4 MiB
    unsigned int*   Wb   = (unsigned int*)(ws + 4 * MiB);           // bf16 3x[D,D]: 1.5 MiB
    unsigned short* WqT  = (unsigned short*)(ws + 5 * MiB + 512*KiB); // 512 KiB
    unsigned short* WkT  = (unsigned short*)(ws + 6 * MiB);         // 512 KiB
    unsigned short* Mb   = (unsigned short*)(ws + 7 * MiB);         // bf16 [D,D]: 512 KiB
    unsigned short* Tb   = (unsigned short*)(ws + 8 * MiB);         // bf16 [C,D]: 4 MiB
    unsigned short* Vb   = (unsigned short*)(ws + 12 * MiB);        // bf16 [C,D]: 4 MiB
    int* counts          = (int*)(ws + 16 * MiB);                   // 400 KB
    unsigned int* bucket = (unsigned int*)(ws + 17 * MiB);          // 12.8 MB

    // 1) W convert + transpose + counts zeroing (one dispatch)
    prep_kernel<<<2048, 256, 0, stream>>>(W_Q, W_K, W_V, Wb, WqT, WkT, counts);

    // 2) pool (2048 blocks) + M = Wq^T@Wk (64 blocks), independent, one dispatch
    pool_m_kernel<<<64 + C_CLUST / 2, 256, 0, stream>>>(
        x_var, cvid, (uint2*)cfb, WqT, WkT, Mb);

    // 3) T = cf@M^T, V = cf@Wv^T
    gemm_tv_kernel<<<dim3(C_CLUST / 64, D_DIM / 64, 2), 256, 0, stream>>>(
        (const unsigned short*)cfb, Mb,
        (const unsigned short*)Wb + 2 * (size_t)D_DIM * D_DIM, Tb, Vb);

    // 4) edge scores + bucket scatter
    score_fill_kernel<<<E_EDGES / 4, 256, 0, stream>>>(
        (const unsigned short*)cfb, Tb, cei, hw, ahp, shv, counts, bucket);

    // 5) per-var gather
    gather_kernel<<<N_VARS / 4, 256, 0, stream>>>(x_var, Vb, counts, bucket,
                                                  (float*)d_out);
}